// Round 1
// baseline (356.195 us; speedup 1.0000x reference)
//
#include <hip/hip_runtime.h>
#include <math.h>

namespace {
constexpr int H  = 8;
constexpr int D  = 64;
constexpr int NB = 32;   // number of 64-blocks along T
constexpr int BS = 64;   // block size
constexpr int QST = 68;  // padded LDS stride (float4-aligned, conflict-light)
}
#define FEPS 1e-6f

// ---------------- Kernel A: block means (float64 for classification fidelity) ----------------
__global__ __launch_bounds__(64) void rep_kernel(const float* __restrict__ q,
                                                 const float* __restrict__ k,
                                                 double* __restrict__ qrep,
                                                 double* __restrict__ krep) {
  int id = blockIdx.x;            // 0..511
  int w  = id >> 8;               // 0: q, 1: k
  int r  = id & 255;              // h*NB + bi
  int h  = r >> 5, bi = r & 31;
  int d  = threadIdx.x;           // 0..63
  const float* src = w ? k : q;
  double s = 0.0;
  for (int t = 0; t < BS; ++t)
    s += (double)src[((bi*BS + t)*H + h)*D + d];
  (w ? krep : qrep)[r*D + d] = s * (1.0/64.0);
}

// ---------------- Kernel B: classification (single block, float64) ----------------
__global__ __launch_bounds__(256) void classify_kernel(const double* __restrict__ qrep,
                                                       const double* __restrict__ krep,
                                                       int* __restrict__ flags) {
  __shared__ double red[256];
  int tid = threadIdx.x;          // row = h*NB + qi
  int h = tid >> 5;
  double bs[NB];
  const double* qr = qrep + tid*D;
  for (int ki = 0; ki < NB; ++ki) {
    const double* kr = krep + (h*NB + ki)*D;
    double s = 0.0;
    for (int d = 0; d < D; ++d) s += qr[d]*kr[d];
    bs[ki] = s * 0.125;           // / sqrt(64)
  }
  double rmin = bs[0], rmax = bs[0];
  for (int i = 1; i < NB; ++i) { rmin = fmin(rmin, bs[i]); rmax = fmax(rmax, bs[i]); }
  // global min over all bscores
  red[tid] = rmin; __syncthreads();
  for (int s = 128; s > 0; s >>= 1) { if (tid < s) red[tid] = fmin(red[tid], red[tid+s]); __syncthreads(); }
  double gmin = red[0]; __syncthreads();
  // softmax (max-subtracted) + unbiased variance
  double ex[NB]; double S = 0.0;
  for (int i = 0; i < NB; ++i) { ex[i] = exp(bs[i] - rmax); S += ex[i]; }
  double mu = 0.0;
  for (int i = 0; i < NB; ++i) { ex[i] /= S; mu += ex[i]; }
  mu *= (1.0/32.0);
  double var = 0.0;
  for (int i = 0; i < NB; ++i) { double dv = ex[i] - mu; var += dv*dv; }
  var *= (1.0/31.0);
  double rng = rmax - gmin;
  if (rng < 1e-6) rng = 1e-6;     // jnp.maximum(max - min, EPS)
  double imp = var * rng;
  red[tid] = imp; __syncthreads();
  for (int s = 128; s > 0; s >>= 1) { if (tid < s) red[tid] = fmin(red[tid], red[tid+s]); __syncthreads(); }
  double imin = red[0]; __syncthreads();
  red[tid] = imp; __syncthreads();
  for (int s = 128; s > 0; s >>= 1) { if (tid < s) red[tid] = fmax(red[tid], red[tid+s]); __syncthreads(); }
  double imax = red[0];
  double impn = (imp - imin) / (imax - imin + 1e-6);
  flags[tid] = (impn >= 0.5) ? 2 : ((impn <= 0.01) ? 0 : 1);
}

// ---------------- Kernel C: per (h,kblock) kv = kf^T v  and k_sum ----------------
__global__ __launch_bounds__(256) void kv_kernel(const float* __restrict__ k,
                                                 const float* __restrict__ v,
                                                 float* __restrict__ kvt,
                                                 float* __restrict__ ksum) {
  __shared__ float kf[BS*D];   // [s][d]
  __shared__ float vv[BS*D];   // [s][c]
  int bid = blockIdx.x;        // h*NB + ki
  int h = bid >> 5, ki = bid & 31;
  int tid = threadIdx.x;
  int s = tid >> 2, cg = tid & 3;
  const float4* kb = (const float4*)(k + ((ki*BS + s)*H + h)*D);
  const float4* vb = (const float4*)(v + ((ki*BS + s)*H + h)*D);
#pragma unroll
  for (int m = 0; m < 4; ++m) {
    float4 kk = kb[cg*4 + m];
    float4 vx = vb[cg*4 + m];
    int c = cg*16 + m*4;
    kf[s*D + c + 0] = kk.x > 0.f ? kk.x + 1.f : expf(kk.x);  // elu(x)+1
    kf[s*D + c + 1] = kk.y > 0.f ? kk.y + 1.f : expf(kk.y);
    kf[s*D + c + 2] = kk.z > 0.f ? kk.z + 1.f : expf(kk.z);
    kf[s*D + c + 3] = kk.w > 0.f ? kk.w + 1.f : expf(kk.w);
    *(float4*)&vv[s*D + c] = vx;
  }
  __syncthreads();
  int d = tid & 63, vg = tid >> 6;
  float acc[16];
#pragma unroll
  for (int j = 0; j < 16; ++j) acc[j] = 0.f;
  float ks = 0.f;
  for (int s2 = 0; s2 < BS; ++s2) {
    float kfv = kf[s2*D + d];
    ks += kfv;
    const float4* vr = (const float4*)&vv[s2*D + vg*16];
    float4 a0 = vr[0], a1 = vr[1], a2 = vr[2], a3 = vr[3];
    acc[0]  += kfv*a0.x; acc[1]  += kfv*a0.y; acc[2]  += kfv*a0.z; acc[3]  += kfv*a0.w;
    acc[4]  += kfv*a1.x; acc[5]  += kfv*a1.y; acc[6]  += kfv*a1.z; acc[7]  += kfv*a1.w;
    acc[8]  += kfv*a2.x; acc[9]  += kfv*a2.y; acc[10] += kfv*a2.z; acc[11] += kfv*a2.w;
    acc[12] += kfv*a3.x; acc[13] += kfv*a3.y; acc[14] += kfv*a3.z; acc[15] += kfv*a3.w;
  }
  float* op = kvt + (bid*D + d)*D + vg*16;
  *(float4*)(op + 0)  = make_float4(acc[0],  acc[1],  acc[2],  acc[3]);
  *(float4*)(op + 4)  = make_float4(acc[4],  acc[5],  acc[6],  acc[7]);
  *(float4*)(op + 8)  = make_float4(acc[8],  acc[9],  acc[10], acc[11]);
  *(float4*)(op + 12) = make_float4(acc[12], acc[13], acc[14], acc[15]);
  if (vg == 0) ksum[bid*D + d] = ks;
}

// ---------------- Kernel D: main per-(h,qblock) kernel ----------------
__global__ __launch_bounds__(256) void main_kernel(
    const float* __restrict__ q, const float* __restrict__ k, const float* __restrict__ v,
    const float* __restrict__ kvt, const float* __restrict__ ksum,
    const int* __restrict__ flags, float* __restrict__ out) {
  __shared__ float bufA[QST*BS];
  __shared__ float bufB[QST*BS];
  __shared__ float bufC[QST*BS];
  __shared__ float ksl[D];
  int bid = blockIdx.x;           // h*NB + qi
  int h = bid >> 5, qi = bid & 31;
  int tid = threadIdx.x;
  int row = tid >> 2, cg = tid & 3, c0 = cg*16;
  int flag = flags[bid];
  float acc[16];
#pragma unroll
  for (int j = 0; j < 16; ++j) acc[j] = 0.f;
  float wsum = 0.f;

  if (flag == 1) {
    // ---- marginal: linear (ELU+1) attention ----
    const float4* qp = (const float4*)(q + ((qi*BS + row)*H + h)*D);
#pragma unroll
    for (int m = 0; m < 4; ++m) {
      float4 qq = qp[cg*4 + m];
      int c = c0 + m*4;
      bufA[row*QST + c + 0] = qq.x > 0.f ? qq.x + 1.f : expf(qq.x);
      bufA[row*QST + c + 1] = qq.y > 0.f ? qq.y + 1.f : expf(qq.y);
      bufA[row*QST + c + 2] = qq.z > 0.f ? qq.z + 1.f : expf(qq.z);
      bufA[row*QST + c + 3] = qq.w > 0.f ? qq.w + 1.f : expf(qq.w);
    }
    __syncthreads();
    for (int ki = 0; ki < NB; ++ki) {
      // stage kv tile (row d = `row`) and k_sum
      const float4* kvsrc = (const float4*)(kvt + ((h*NB + ki)*D + row)*D + c0);
      float4 t0 = kvsrc[0], t1 = kvsrc[1], t2 = kvsrc[2], t3 = kvsrc[3];
      *(float4*)&bufB[row*QST + c0 + 0]  = t0;
      *(float4*)&bufB[row*QST + c0 + 4]  = t1;
      *(float4*)&bufB[row*QST + c0 + 8]  = t2;
      *(float4*)&bufB[row*QST + c0 + 12] = t3;
      if (tid < 16)
        *(float4*)&ksl[tid*4] = ((const float4*)(ksum + (h*NB + ki)*D))[tid];
      __syncthreads();
      float den = FEPS;
#pragma unroll 8
      for (int d = 0; d < D; ++d) den += bufA[row*QST + d] * ksl[d];
      wsum += den;
      float inv = 1.0f / den;
      float num[16];
#pragma unroll
      for (int j = 0; j < 16; ++j) num[j] = 0.f;
#pragma unroll 4
      for (int d = 0; d < D; ++d) {
        float a = bufA[row*QST + d];
        const float4* br = (const float4*)&bufB[d*QST + c0];
        float4 b0 = br[0], b1 = br[1], b2 = br[2], b3 = br[3];
        num[0]  += a*b0.x; num[1]  += a*b0.y; num[2]  += a*b0.z; num[3]  += a*b0.w;
        num[4]  += a*b1.x; num[5]  += a*b1.y; num[6]  += a*b1.z; num[7]  += a*b1.w;
        num[8]  += a*b2.x; num[9]  += a*b2.y; num[10] += a*b2.z; num[11] += a*b2.w;
        num[12] += a*b3.x; num[13] += a*b3.y; num[14] += a*b3.z; num[15] += a*b3.w;
      }
#pragma unroll
      for (int j = 0; j < 16; ++j) acc[j] += num[j]*inv;
      __syncthreads();
    }
  } else if (flag == 2) {
    // ---- critical: per-block-pair softmax attention ----
    const float4* qp = (const float4*)(q + ((qi*BS + row)*H + h)*D);
#pragma unroll
    for (int m = 0; m < 4; ++m) {
      float4 qq = qp[cg*4 + m];
      int c = c0 + m*4;
      bufA[row*QST + c + 0] = qq.x*0.125f;   // scale = 1/(sqrt(D)*TEMP)
      bufA[row*QST + c + 1] = qq.y*0.125f;
      bufA[row*QST + c + 2] = qq.z*0.125f;
      bufA[row*QST + c + 3] = qq.w*0.125f;
    }
    __syncthreads();
    for (int ki = 0; ki < NB; ++ki) {
      const float4* kp = (const float4*)(k + ((ki*BS + row)*H + h)*D);
#pragma unroll
      for (int m = 0; m < 4; ++m)
        *(float4*)&bufB[row*QST + c0 + m*4] = kp[cg*4 + m];
      __syncthreads();
      float sc[16];
#pragma unroll
      for (int j = 0; j < 16; ++j) sc[j] = 0.f;
      for (int d = 0; d < D; ++d) {
        float a = bufA[row*QST + d];
#pragma unroll
        for (int j = 0; j < 16; ++j)
          sc[j] += a * bufB[(c0 + j)*QST + d];
      }
#pragma unroll
      for (int j = 0; j < 16; ++j) bufC[row*QST + c0 + j] = sc[j];
      __syncthreads();
      // stage V into bufB (kb no longer needed); row softmax stats from bufC
      const float4* vp = (const float4*)(v + ((ki*BS + row)*H + h)*D);
      float4 vstage[4];
#pragma unroll
      for (int m = 0; m < 4; ++m) vstage[m] = vp[cg*4 + m];
      float mx = -3.0e38f;
      for (int s2 = 0; s2 < BS; ++s2) mx = fmaxf(mx, bufC[row*QST + s2]);
      float Ssum = 0.f;
      for (int s2 = 0; s2 < BS; ++s2) Ssum += expf(bufC[row*QST + s2] - mx);
#pragma unroll
      for (int m = 0; m < 4; ++m) *(float4*)&bufB[row*QST + c0 + m*4] = vstage[m];
      __syncthreads();
      float inv = 1.0f / Ssum;
      float ps = 0.f;
      for (int s2 = 0; s2 < BS; ++s2) {
        float p = expf(bufC[row*QST + s2] - mx) * inv;
        ps += p;
        const float4* vr = (const float4*)&bufB[s2*QST + c0];
        float4 a0 = vr[0], a1 = vr[1], a2 = vr[2], a3 = vr[3];
        acc[0]  += p*a0.x; acc[1]  += p*a0.y; acc[2]  += p*a0.z; acc[3]  += p*a0.w;
        acc[4]  += p*a1.x; acc[5]  += p*a1.y; acc[6]  += p*a1.z; acc[7]  += p*a1.w;
        acc[8]  += p*a2.x; acc[9]  += p*a2.y; acc[10] += p*a2.z; acc[11] += p*a2.w;
        acc[12] += p*a3.x; acc[13] += p*a3.y; acc[14] += p*a3.z; acc[15] += p*a3.w;
      }
      wsum += ps;
      __syncthreads();
    }
  }
  // epilogue (negligible rows fall through with acc=0, wsum=0 -> exact 0)
  float wd = 1.0f / (wsum + FEPS);
  float* op = out + ((qi*BS + row)*H + h)*D + c0;
  *(float4*)(op + 0)  = make_float4(acc[0]*wd,  acc[1]*wd,  acc[2]*wd,  acc[3]*wd);
  *(float4*)(op + 4)  = make_float4(acc[4]*wd,  acc[5]*wd,  acc[6]*wd,  acc[7]*wd);
  *(float4*)(op + 8)  = make_float4(acc[8]*wd,  acc[9]*wd,  acc[10]*wd, acc[11]*wd);
  *(float4*)(op + 12) = make_float4(acc[12]*wd, acc[13]*wd, acc[14]*wd, acc[15]*wd);
}

extern "C" void kernel_launch(void* const* d_in, const int* in_sizes, int n_in,
                              void* d_out, int out_size, void* d_ws, size_t ws_size,
                              hipStream_t stream) {
  const float* q = (const float*)d_in[0];
  const float* k = (const float*)d_in[1];
  const float* v = (const float*)d_in[2];
  float* out = (float*)d_out;
  char* ws = (char*)d_ws;
  // workspace layout (16B-aligned offsets), total ~4.4 MB
  double* qrep = (double*)(ws + 0);         // 16384 doubles
  double* krep = (double*)(ws + 131072);    // 16384 doubles
  int*    flg  = (int*)   (ws + 262144);    // 256 ints
  float*  ksw  = (float*) (ws + 263168);    // 16384 floats
  float*  kvw  = (float*) (ws + 328704);    // 1048576 floats

  rep_kernel<<<512, 64, 0, stream>>>(q, k, qrep, krep);
  classify_kernel<<<1, 256, 0, stream>>>(qrep, krep, flg);
  kv_kernel<<<256, 256, 0, stream>>>(k, v, kvw, ksw);
  main_kernel<<<256, 256, 0, stream>>>(q, k, v, kvw, ksw, flg, out);
}

// Round 2
// 221.465 us; speedup vs baseline: 1.6084x; 1.6084x over previous
//
#include <hip/hip_runtime.h>
#include <math.h>

namespace {
constexpr int H  = 8;
constexpr int D  = 64;
constexpr int NB = 32;   // number of 64-blocks along T
constexpr int BS = 64;   // block size
constexpr int QST = 68;  // padded LDS stride (float4-aligned, conflict-light)
}
#define FEPS 1e-6f

// ---------------- Kernel A: block means (float64 for classification fidelity) ----------------
__global__ __launch_bounds__(64) void rep_kernel(const float* __restrict__ q,
                                                 const float* __restrict__ k,
                                                 double* __restrict__ qrep,
                                                 double* __restrict__ krep) {
  int id = blockIdx.x;            // 0..511
  int w  = id >> 8;               // 0: q, 1: k
  int r  = id & 255;              // h*NB + bi
  int h  = r >> 5, bi = r & 31;
  int d  = threadIdx.x;           // 0..63
  const float* src = w ? k : q;
  double s = 0.0;
  for (int t = 0; t < BS; ++t)
    s += (double)src[((bi*BS + t)*H + h)*D + d];
  (w ? krep : qrep)[r*D + d] = s * (1.0/64.0);
}

// ---------------- Kernel B1: bscores (parallel f64 dots, no register arrays) ----------------
__global__ __launch_bounds__(256) void bscore_kernel(const double* __restrict__ qrep,
                                                     const double* __restrict__ krep,
                                                     double* __restrict__ bsc) {
  int tid = threadIdx.x;
  int lr = tid >> 5, ki = tid & 31;      // 8 rows per block, 32 ki per row
  int r = blockIdx.x * 8 + lr;           // row = h*NB + qi, 0..255
  int h = r >> 5;
  const double* qr = qrep + r*D;
  const double* kr = krep + (h*NB + ki)*D;
  double s = 0.0;
#pragma unroll 16
  for (int d = 0; d < D; ++d) s += qr[d]*kr[d];
  bsc[r*NB + ki] = s * 0.125;            // / sqrt(64)
}

// ---------------- Kernel B2: classification (single block, streaming passes, f64) ----------------
__global__ __launch_bounds__(256) void classify2_kernel(const double* __restrict__ bsc,
                                                        int* __restrict__ flags) {
  __shared__ double red[256];
  int tid = threadIdx.x;                 // row = h*NB + qi
  const double* row = bsc + tid*NB;
  // pass 1: row min/max
  double rmax = -1.0e300, rmin = 1.0e300;
#pragma unroll 8
  for (int i = 0; i < NB; ++i) { double b = row[i]; rmax = fmax(rmax, b); rmin = fmin(rmin, b); }
  red[tid] = rmin; __syncthreads();
  for (int s = 128; s > 0; s >>= 1) { if (tid < s) red[tid] = fmin(red[tid], red[tid+s]); __syncthreads(); }
  double gmin = red[0]; __syncthreads();
  // pass 2: softmax denominator
  double S = 0.0;
#pragma unroll 8
  for (int i = 0; i < NB; ++i) S += exp(row[i] - rmax);
  double invS = 1.0 / S;
  // pass 3: mean of p (matches jnp.var's computed mean, not assumed 1/32)
  double psum = 0.0;
#pragma unroll 8
  for (int i = 0; i < NB; ++i) psum += exp(row[i] - rmax) * invS;
  double mu = psum * (1.0/32.0);
  // pass 4: unbiased variance
  double var = 0.0;
#pragma unroll 8
  for (int i = 0; i < NB; ++i) {
    double dv = exp(row[i] - rmax) * invS - mu;
    var += dv*dv;
  }
  var *= (1.0/31.0);
  double rng = rmax - gmin;
  if (rng < 1e-6) rng = 1e-6;            // jnp.maximum(max - min, EPS)
  double imp = var * rng;
  red[tid] = imp; __syncthreads();
  for (int s = 128; s > 0; s >>= 1) { if (tid < s) red[tid] = fmin(red[tid], red[tid+s]); __syncthreads(); }
  double imin = red[0]; __syncthreads();
  red[tid] = imp; __syncthreads();
  for (int s = 128; s > 0; s >>= 1) { if (tid < s) red[tid] = fmax(red[tid], red[tid+s]); __syncthreads(); }
  double imax = red[0];
  double impn = (imp - imin) / (imax - imin + 1e-6);
  flags[tid] = (impn >= 0.5) ? 2 : ((impn <= 0.01) ? 0 : 1);
}

// ---------------- Kernel C: per (h,kblock) kv = kf^T v  and k_sum ----------------
__global__ __launch_bounds__(256) void kv_kernel(const float* __restrict__ k,
                                                 const float* __restrict__ v,
                                                 float* __restrict__ kvt,
                                                 float* __restrict__ ksum) {
  __shared__ float kf[BS*D];   // [s][d]
  __shared__ float vv[BS*D];   // [s][c]
  int bid = blockIdx.x;        // h*NB + ki
  int h = bid >> 5, ki = bid & 31;
  int tid = threadIdx.x;
  int s = tid >> 2, cg = tid & 3;
  const float4* kb = (const float4*)(k + ((ki*BS + s)*H + h)*D);
  const float4* vb = (const float4*)(v + ((ki*BS + s)*H + h)*D);
#pragma unroll
  for (int m = 0; m < 4; ++m) {
    float4 kk = kb[cg*4 + m];
    float4 vx = vb[cg*4 + m];
    int c = cg*16 + m*4;
    kf[s*D + c + 0] = kk.x > 0.f ? kk.x + 1.f : expf(kk.x);  // elu(x)+1
    kf[s*D + c + 1] = kk.y > 0.f ? kk.y + 1.f : expf(kk.y);
    kf[s*D + c + 2] = kk.z > 0.f ? kk.z + 1.f : expf(kk.z);
    kf[s*D + c + 3] = kk.w > 0.f ? kk.w + 1.f : expf(kk.w);
    *(float4*)&vv[s*D + c] = vx;
  }
  __syncthreads();
  int d = tid & 63, vg = tid >> 6;
  float acc[16];
#pragma unroll
  for (int j = 0; j < 16; ++j) acc[j] = 0.f;
  float ks = 0.f;
  for (int s2 = 0; s2 < BS; ++s2) {
    float kfv = kf[s2*D + d];
    ks += kfv;
    const float4* vr = (const float4*)&vv[s2*D + vg*16];
    float4 a0 = vr[0], a1 = vr[1], a2 = vr[2], a3 = vr[3];
    acc[0]  += kfv*a0.x; acc[1]  += kfv*a0.y; acc[2]  += kfv*a0.z; acc[3]  += kfv*a0.w;
    acc[4]  += kfv*a1.x; acc[5]  += kfv*a1.y; acc[6]  += kfv*a1.z; acc[7]  += kfv*a1.w;
    acc[8]  += kfv*a2.x; acc[9]  += kfv*a2.y; acc[10] += kfv*a2.z; acc[11] += kfv*a2.w;
    acc[12] += kfv*a3.x; acc[13] += kfv*a3.y; acc[14] += kfv*a3.z; acc[15] += kfv*a3.w;
  }
  float* op = kvt + (bid*D + d)*D + vg*16;
  *(float4*)(op + 0)  = make_float4(acc[0],  acc[1],  acc[2],  acc[3]);
  *(float4*)(op + 4)  = make_float4(acc[4],  acc[5],  acc[6],  acc[7]);
  *(float4*)(op + 8)  = make_float4(acc[8],  acc[9],  acc[10], acc[11]);
  *(float4*)(op + 12) = make_float4(acc[12], acc[13], acc[14], acc[15]);
  if (vg == 0) ksum[bid*D + d] = ks;
}

// ---------------- Kernel D: main per-(h,qblock) kernel ----------------
__global__ __launch_bounds__(256) void main_kernel(
    const float* __restrict__ q, const float* __restrict__ k, const float* __restrict__ v,
    const float* __restrict__ kvt, const float* __restrict__ ksum,
    const int* __restrict__ flags, float* __restrict__ out) {
  __shared__ float bufA[QST*BS];
  __shared__ float bufB[QST*BS];
  __shared__ float bufC[QST*BS];
  __shared__ float ksl[D];
  int bid = blockIdx.x;           // h*NB + qi
  int h = bid >> 5, qi = bid & 31;
  int tid = threadIdx.x;
  int row = tid >> 2, cg = tid & 3, c0 = cg*16;
  int flag = flags[bid];
  float acc[16];
#pragma unroll
  for (int j = 0; j < 16; ++j) acc[j] = 0.f;
  float wsum = 0.f;

  if (flag == 1) {
    // ---- marginal: linear (ELU+1) attention ----
    const float4* qp = (const float4*)(q + ((qi*BS + row)*H + h)*D);
#pragma unroll
    for (int m = 0; m < 4; ++m) {
      float4 qq = qp[cg*4 + m];
      int c = c0 + m*4;
      bufA[row*QST + c + 0] = qq.x > 0.f ? qq.x + 1.f : expf(qq.x);
      bufA[row*QST + c + 1] = qq.y > 0.f ? qq.y + 1.f : expf(qq.y);
      bufA[row*QST + c + 2] = qq.z > 0.f ? qq.z + 1.f : expf(qq.z);
      bufA[row*QST + c + 3] = qq.w > 0.f ? qq.w + 1.f : expf(qq.w);
    }
    __syncthreads();
    for (int ki = 0; ki < NB; ++ki) {
      // stage kv tile (row d = `row`) and k_sum
      const float4* kvsrc = (const float4*)(kvt + ((h*NB + ki)*D + row)*D + c0);
      float4 t0 = kvsrc[0], t1 = kvsrc[1], t2 = kvsrc[2], t3 = kvsrc[3];
      *(float4*)&bufB[row*QST + c0 + 0]  = t0;
      *(float4*)&bufB[row*QST + c0 + 4]  = t1;
      *(float4*)&bufB[row*QST + c0 + 8]  = t2;
      *(float4*)&bufB[row*QST + c0 + 12] = t3;
      if (tid < 16)
        *(float4*)&ksl[tid*4] = ((const float4*)(ksum + (h*NB + ki)*D))[tid];
      __syncthreads();
      float den = FEPS;
#pragma unroll 8
      for (int d = 0; d < D; ++d) den += bufA[row*QST + d] * ksl[d];
      wsum += den;
      float inv = 1.0f / den;
      float num[16];
#pragma unroll
      for (int j = 0; j < 16; ++j) num[j] = 0.f;
#pragma unroll 4
      for (int d = 0; d < D; ++d) {
        float a = bufA[row*QST + d];
        const float4* br = (const float4*)&bufB[d*QST + c0];
        float4 b0 = br[0], b1 = br[1], b2 = br[2], b3 = br[3];
        num[0]  += a*b0.x; num[1]  += a*b0.y; num[2]  += a*b0.z; num[3]  += a*b0.w;
        num[4]  += a*b1.x; num[5]  += a*b1.y; num[6]  += a*b1.z; num[7]  += a*b1.w;
        num[8]  += a*b2.x; num[9]  += a*b2.y; num[10] += a*b2.z; num[11] += a*b2.w;
        num[12] += a*b3.x; num[13] += a*b3.y; num[14] += a*b3.z; num[15] += a*b3.w;
      }
#pragma unroll
      for (int j = 0; j < 16; ++j) acc[j] += num[j]*inv;
      __syncthreads();
    }
  } else if (flag == 2) {
    // ---- critical: per-block-pair softmax attention ----
    const float4* qp = (const float4*)(q + ((qi*BS + row)*H + h)*D);
#pragma unroll
    for (int m = 0; m < 4; ++m) {
      float4 qq = qp[cg*4 + m];
      int c = c0 + m*4;
      bufA[row*QST + c + 0] = qq.x*0.125f;   // scale = 1/(sqrt(D)*TEMP)
      bufA[row*QST + c + 1] = qq.y*0.125f;
      bufA[row*QST + c + 2] = qq.z*0.125f;
      bufA[row*QST + c + 3] = qq.w*0.125f;
    }
    __syncthreads();
    for (int ki = 0; ki < NB; ++ki) {
      const float4* kp = (const float4*)(k + ((ki*BS + row)*H + h)*D);
#pragma unroll
      for (int m = 0; m < 4; ++m)
        *(float4*)&bufB[row*QST + c0 + m*4] = kp[cg*4 + m];
      __syncthreads();
      float sc[16];
#pragma unroll
      for (int j = 0; j < 16; ++j) sc[j] = 0.f;
      for (int d = 0; d < D; ++d) {
        float a = bufA[row*QST + d];
#pragma unroll
        for (int j = 0; j < 16; ++j)
          sc[j] += a * bufB[(c0 + j)*QST + d];
      }
#pragma unroll
      for (int j = 0; j < 16; ++j) bufC[row*QST + c0 + j] = sc[j];
      __syncthreads();
      // stage V into bufB (kb no longer needed); row softmax stats from bufC
      const float4* vp = (const float4*)(v + ((ki*BS + row)*H + h)*D);
      float4 vstage[4];
#pragma unroll
      for (int m = 0; m < 4; ++m) vstage[m] = vp[cg*4 + m];
      float mx = -3.0e38f;
      for (int s2 = 0; s2 < BS; ++s2) mx = fmaxf(mx, bufC[row*QST + s2]);
      float Ssum = 0.f;
      for (int s2 = 0; s2 < BS; ++s2) Ssum += expf(bufC[row*QST + s2] - mx);
#pragma unroll
      for (int m = 0; m < 4; ++m) *(float4*)&bufB[row*QST + c0 + m*4] = vstage[m];
      __syncthreads();
      float inv = 1.0f / Ssum;
      float ps = 0.f;
      for (int s2 = 0; s2 < BS; ++s2) {
        float p = expf(bufC[row*QST + s2] - mx) * inv;
        ps += p;
        const float4* vr = (const float4*)&bufB[s2*QST + c0];
        float4 a0 = vr[0], a1 = vr[1], a2 = vr[2], a3 = vr[3];
        acc[0]  += p*a0.x; acc[1]  += p*a0.y; acc[2]  += p*a0.z; acc[3]  += p*a0.w;
        acc[4]  += p*a1.x; acc[5]  += p*a1.y; acc[6]  += p*a1.z; acc[7]  += p*a1.w;
        acc[8]  += p*a2.x; acc[9]  += p*a2.y; acc[10] += p*a2.z; acc[11] += p*a2.w;
        acc[12] += p*a3.x; acc[13] += p*a3.y; acc[14] += p*a3.z; acc[15] += p*a3.w;
      }
      wsum += ps;
      __syncthreads();
    }
  }
  // epilogue (negligible rows fall through with acc=0, wsum=0 -> exact 0)
  float wd = 1.0f / (wsum + FEPS);
  float* op = out + ((qi*BS + row)*H + h)*D + c0;
  *(float4*)(op + 0)  = make_float4(acc[0]*wd,  acc[1]*wd,  acc[2]*wd,  acc[3]*wd);
  *(float4*)(op + 4)  = make_float4(acc[4]*wd,  acc[5]*wd,  acc[6]*wd,  acc[7]*wd);
  *(float4*)(op + 8)  = make_float4(acc[8]*wd,  acc[9]*wd,  acc[10]*wd, acc[11]*wd);
  *(float4*)(op + 12) = make_float4(acc[12]*wd, acc[13]*wd, acc[14]*wd, acc[15]*wd);
}

extern "C" void kernel_launch(void* const* d_in, const int* in_sizes, int n_in,
                              void* d_out, int out_size, void* d_ws, size_t ws_size,
                              hipStream_t stream) {
  const float* q = (const float*)d_in[0];
  const float* k = (const float*)d_in[1];
  const float* v = (const float*)d_in[2];
  float* out = (float*)d_out;
  char* ws = (char*)d_ws;
  // workspace layout (16B-aligned offsets)
  double* qrep = (double*)(ws + 0);         // 16384 doubles
  double* krep = (double*)(ws + 131072);    // 16384 doubles
  int*    flg  = (int*)   (ws + 262144);    // 256 ints
  float*  ksw  = (float*) (ws + 263168);    // 16384 floats
  float*  kvw  = (float*) (ws + 328704);    // 1048576 floats
  double* bsc  = (double*)(ws + 4523008);   // 8192 doubles

  rep_kernel<<<512, 64, 0, stream>>>(q, k, qrep, krep);
  bscore_kernel<<<32, 256, 0, stream>>>(qrep, krep, bsc);
  classify2_kernel<<<1, 256, 0, stream>>>(bsc, flg);
  kv_kernel<<<256, 256, 0, stream>>>(k, v, kvw, ksw);
  main_kernel<<<256, 256, 0, stream>>>(q, k, v, kvw, ksw, flg, out);
}

// Round 3
// 180.991 us; speedup vs baseline: 1.9680x; 1.2236x over previous
//
#include <hip/hip_runtime.h>
#include <math.h>

namespace {
constexpr int H  = 8;
constexpr int D  = 64;
constexpr int NB = 32;   // number of 64-blocks along T
constexpr int BS = 64;   // block size
constexpr int QST = 68;  // padded LDS stride
}
#define FEPS 1e-6f

// ---------------- Kernel P: fused prologue ----------------
// blocks 0..255  : kv = (elu(k)+1)^T v, k_sum, and krep (f64 block mean of raw k)
// blocks 256..511: qrep (f64 block mean of q)
__global__ __launch_bounds__(256) void prep_kernel(const float* __restrict__ q,
                                                   const float* __restrict__ k,
                                                   const float* __restrict__ v,
                                                   float* __restrict__ kvt,
                                                   float* __restrict__ ksum,
                                                   double* __restrict__ qrep,
                                                   double* __restrict__ krep) {
  __shared__ float smem[3*BS*D];          // 48 KB
  int bid = blockIdx.x;
  int tid = threadIdx.x;
  if (bid >= 256) {
    // ---- q block means ----
    double* qred = (double*)smem;
    int r = bid - 256;                    // h*NB + bi
    int h = r >> 5, bi = r & 31;
    int d = tid & 63, quarter = tid >> 6;
    double s = 0.0;
    for (int t = quarter*16; t < quarter*16 + 16; ++t)
      s += (double)q[((bi*BS + t)*H + h)*D + d];
    qred[quarter*64 + d] = s;
    __syncthreads();
    if (tid < 64)
      qrep[r*D + tid] = (qred[tid] + qred[64+tid] + qred[128+tid] + qred[192+tid]) * (1.0/64.0);
    return;
  }
  // ---- kv path ----
  float* kf   = smem;                     // [s][d] elu(k)+1
  float* vv   = smem + BS*D;              // [s][c]
  float* kraw = smem + 2*BS*D;            // [s][d] raw k
  int h = bid >> 5, ki = bid & 31;
  int s = tid >> 2, cg = tid & 3;
  const float4* kb = (const float4*)(k + ((ki*BS + s)*H + h)*D);
  const float4* vb = (const float4*)(v + ((ki*BS + s)*H + h)*D);
#pragma unroll
  for (int m = 0; m < 4; ++m) {
    float4 kk = kb[cg*4 + m];
    float4 vx = vb[cg*4 + m];
    int c = cg*16 + m*4;
    *(float4*)&kraw[s*D + c] = kk;
    kf[s*D + c + 0] = kk.x > 0.f ? kk.x + 1.f : expf(kk.x);
    kf[s*D + c + 1] = kk.y > 0.f ? kk.y + 1.f : expf(kk.y);
    kf[s*D + c + 2] = kk.z > 0.f ? kk.z + 1.f : expf(kk.z);
    kf[s*D + c + 3] = kk.w > 0.f ? kk.w + 1.f : expf(kk.w);
    *(float4*)&vv[s*D + c] = vx;
  }
  __syncthreads();
  int d = tid & 63, vg = tid >> 6;
  float acc[16];
#pragma unroll
  for (int j = 0; j < 16; ++j) acc[j] = 0.f;
  float ks = 0.f;
#pragma unroll 4
  for (int s2 = 0; s2 < BS; ++s2) {
    float kfv = kf[s2*D + d];
    ks += kfv;
    const float4* vr = (const float4*)&vv[s2*D + vg*16];
    float4 a0 = vr[0], a1 = vr[1], a2 = vr[2], a3 = vr[3];
    acc[0]  += kfv*a0.x; acc[1]  += kfv*a0.y; acc[2]  += kfv*a0.z; acc[3]  += kfv*a0.w;
    acc[4]  += kfv*a1.x; acc[5]  += kfv*a1.y; acc[6]  += kfv*a1.z; acc[7]  += kfv*a1.w;
    acc[8]  += kfv*a2.x; acc[9]  += kfv*a2.y; acc[10] += kfv*a2.z; acc[11] += kfv*a2.w;
    acc[12] += kfv*a3.x; acc[13] += kfv*a3.y; acc[14] += kfv*a3.z; acc[15] += kfv*a3.w;
  }
  float* op = kvt + (bid*D + d)*D + vg*16;
  *(float4*)(op + 0)  = make_float4(acc[0],  acc[1],  acc[2],  acc[3]);
  *(float4*)(op + 4)  = make_float4(acc[4],  acc[5],  acc[6],  acc[7]);
  *(float4*)(op + 8)  = make_float4(acc[8],  acc[9],  acc[10], acc[11]);
  *(float4*)(op + 12) = make_float4(acc[12], acc[13], acc[14], acc[15]);
  if (vg == 0) {
    ksum[bid*D + d] = ks;
    double m = 0.0;
    for (int s2 = 0; s2 < BS; ++s2) m += (double)kraw[s2*D + d];
    krep[bid*D + d] = m * (1.0/64.0);
  }
}

// ---------------- Kernel B1: bscores (parallel f64 dots) ----------------
__global__ __launch_bounds__(256) void bscore_kernel(const double* __restrict__ qrep,
                                                     const double* __restrict__ krep,
                                                     double* __restrict__ bsc) {
  int tid = threadIdx.x;
  int lr = tid >> 5, ki = tid & 31;
  int r = blockIdx.x * 8 + lr;
  int h = r >> 5;
  const double* qr = qrep + r*D;
  const double* kr = krep + (h*NB + ki)*D;
  double s = 0.0;
#pragma unroll 16
  for (int d = 0; d < D; ++d) s += qr[d]*kr[d];
  bsc[r*NB + ki] = s * 0.125;
}

// ---------------- Kernel B2: classification (single block, streaming, f64) ----------------
__global__ __launch_bounds__(256) void classify2_kernel(const double* __restrict__ bsc,
                                                        int* __restrict__ flags) {
  __shared__ double red[256];
  int tid = threadIdx.x;
  const double* row = bsc + tid*NB;
  double rmax = -1.0e300, rmin = 1.0e300;
#pragma unroll 8
  for (int i = 0; i < NB; ++i) { double b = row[i]; rmax = fmax(rmax, b); rmin = fmin(rmin, b); }
  red[tid] = rmin; __syncthreads();
  for (int s = 128; s > 0; s >>= 1) { if (tid < s) red[tid] = fmin(red[tid], red[tid+s]); __syncthreads(); }
  double gmin = red[0]; __syncthreads();
  double S = 0.0;
#pragma unroll 8
  for (int i = 0; i < NB; ++i) S += exp(row[i] - rmax);
  double invS = 1.0 / S;
  double psum = 0.0;
#pragma unroll 8
  for (int i = 0; i < NB; ++i) psum += exp(row[i] - rmax) * invS;
  double mu = psum * (1.0/32.0);
  double var = 0.0;
#pragma unroll 8
  for (int i = 0; i < NB; ++i) {
    double dv = exp(row[i] - rmax) * invS - mu;
    var += dv*dv;
  }
  var *= (1.0/31.0);
  double rng = rmax - gmin;
  if (rng < 1e-6) rng = 1e-6;
  double imp = var * rng;
  red[tid] = imp; __syncthreads();
  for (int s = 128; s > 0; s >>= 1) { if (tid < s) red[tid] = fmin(red[tid], red[tid+s]); __syncthreads(); }
  double imin = red[0]; __syncthreads();
  red[tid] = imp; __syncthreads();
  for (int s = 128; s > 0; s >>= 1) { if (tid < s) red[tid] = fmax(red[tid], red[tid+s]); __syncthreads(); }
  double imax = red[0];
  double impn = (imp - imin) / (imax - imin + 1e-6);
  flags[tid] = (impn >= 0.5) ? 2 : ((impn <= 0.01) ? 0 : 1);
}

// ---------------- Kernel D: main, split-K over ki ----------------
// blockIdx = chunk*256 + (h*NB+qi). Writes partial acc/wsum (or out directly).
__global__ __launch_bounds__(256) void main_kernel(
    const float* __restrict__ q, const float* __restrict__ k, const float* __restrict__ v,
    const float* __restrict__ kvt, const float* __restrict__ ksum,
    const int* __restrict__ flags,
    float* __restrict__ pacc, float* __restrict__ pwsum,
    float* __restrict__ outDirect, int kn) {
  __shared__ float bufA[QST*BS];
  __shared__ float bufB[QST*BS];
  __shared__ float ksl[D];
  int bid = blockIdx.x & 255;
  int chunk = blockIdx.x >> 8;
  int k0 = chunk * kn;
  int h = bid >> 5, qi = bid & 31;
  int tid = threadIdx.x;
  int row = tid >> 2, cg = tid & 3, c0 = cg*16;
  int lane = tid & 63;
  int flag = flags[bid];
  float acc[16];
#pragma unroll
  for (int j = 0; j < 16; ++j) acc[j] = 0.f;
  float wsum = 0.f;

  if (flag == 1) {
    // ---- marginal: linear (ELU+1) attention ----
    const float4* qp = (const float4*)(q + ((qi*BS + row)*H + h)*D);
#pragma unroll
    for (int m = 0; m < 4; ++m) {
      float4 qq = qp[cg*4 + m];
      int c = c0 + m*4;
      bufA[row*QST + c + 0] = qq.x > 0.f ? qq.x + 1.f : expf(qq.x);
      bufA[row*QST + c + 1] = qq.y > 0.f ? qq.y + 1.f : expf(qq.y);
      bufA[row*QST + c + 2] = qq.z > 0.f ? qq.z + 1.f : expf(qq.z);
      bufA[row*QST + c + 3] = qq.w > 0.f ? qq.w + 1.f : expf(qq.w);
    }
    __syncthreads();
    for (int ki = k0; ki < k0 + kn; ++ki) {
      const float4* kvsrc = (const float4*)(kvt + ((h*NB + ki)*D + row)*D + c0);
      float4 t0 = kvsrc[0], t1 = kvsrc[1], t2 = kvsrc[2], t3 = kvsrc[3];
      *(float4*)&bufB[row*QST + c0 + 0]  = t0;
      *(float4*)&bufB[row*QST + c0 + 4]  = t1;
      *(float4*)&bufB[row*QST + c0 + 8]  = t2;
      *(float4*)&bufB[row*QST + c0 + 12] = t3;
      if (tid < 16)
        *(float4*)&ksl[tid*4] = ((const float4*)(ksum + (h*NB + ki)*D))[tid];
      __syncthreads();
      float den = FEPS;
#pragma unroll 8
      for (int d = 0; d < D; ++d) den += bufA[row*QST + d] * ksl[d];
      wsum += den;
      float inv = 1.0f / den;
      float num[16];
#pragma unroll
      for (int j = 0; j < 16; ++j) num[j] = 0.f;
#pragma unroll 4
      for (int d = 0; d < D; ++d) {
        float a = bufA[row*QST + d];
        const float4* br = (const float4*)&bufB[d*QST + c0];
        float4 b0 = br[0], b1 = br[1], b2 = br[2], b3 = br[3];
        num[0]  += a*b0.x; num[1]  += a*b0.y; num[2]  += a*b0.z; num[3]  += a*b0.w;
        num[4]  += a*b1.x; num[5]  += a*b1.y; num[6]  += a*b1.z; num[7]  += a*b1.w;
        num[8]  += a*b2.x; num[9]  += a*b2.y; num[10] += a*b2.z; num[11] += a*b2.w;
        num[12] += a*b3.x; num[13] += a*b3.y; num[14] += a*b3.z; num[15] += a*b3.w;
      }
#pragma unroll
      for (int j = 0; j < 16; ++j) acc[j] += num[j]*inv;
      __syncthreads();
    }
  } else if (flag == 2) {
    // ---- critical: per-block-pair softmax attention (scores in registers) ----
    const float4* qp = (const float4*)(q + ((qi*BS + row)*H + h)*D);
#pragma unroll
    for (int m = 0; m < 4; ++m) {
      float4 qq = qp[cg*4 + m];
      int c = c0 + m*4;
      bufA[row*QST + c + 0] = qq.x*0.125f;
      bufA[row*QST + c + 1] = qq.y*0.125f;
      bufA[row*QST + c + 2] = qq.z*0.125f;
      bufA[row*QST + c + 3] = qq.w*0.125f;
    }
    __syncthreads();
    for (int ki = k0; ki < k0 + kn; ++ki) {
      const float4* kp = (const float4*)(k + ((ki*BS + row)*H + h)*D);
#pragma unroll
      for (int m = 0; m < 4; ++m)
        *(float4*)&bufB[row*QST + c0 + m*4] = kp[cg*4 + m];
      __syncthreads();
      float sc[16];
#pragma unroll
      for (int j = 0; j < 16; ++j) sc[j] = 0.f;
      for (int d = 0; d < D; ++d) {
        float a = bufA[row*QST + d];
#pragma unroll
        for (int j = 0; j < 16; ++j)
          sc[j] += a * bufB[(c0 + j)*QST + d];
      }
      // row softmax stats across the 4 lanes of this row (lanes row*4+0..3)
      float mx = sc[0];
#pragma unroll
      for (int j = 1; j < 16; ++j) mx = fmaxf(mx, sc[j]);
      mx = fmaxf(mx, __shfl_xor(mx, 1, 64));
      mx = fmaxf(mx, __shfl_xor(mx, 2, 64));
      float es = 0.f;
      float p[16];
#pragma unroll
      for (int j = 0; j < 16; ++j) { p[j] = expf(sc[j] - mx); es += p[j]; }
      es += __shfl_xor(es, 1, 64);
      es += __shfl_xor(es, 2, 64);
      float inv = 1.0f / es;
#pragma unroll
      for (int j = 0; j < 16; ++j) p[j] *= inv;
      wsum += es * inv;   // row sum of p (~1.0)
      __syncthreads();
      // stage V over K
      const float4* vp = (const float4*)(v + ((ki*BS + row)*H + h)*D);
#pragma unroll
      for (int m = 0; m < 4; ++m)
        *(float4*)&bufB[row*QST + c0 + m*4] = vp[cg*4 + m];
      __syncthreads();
      for (int s2 = 0; s2 < BS; ++s2) {
        int g = s2 >> 4, jj = s2 & 15;
        float pv = __shfl(p[jj], (lane & ~3) | g, 64);
        const float4* vr = (const float4*)&bufB[s2*QST + c0];
        float4 a0 = vr[0], a1 = vr[1], a2 = vr[2], a3 = vr[3];
        acc[0]  += pv*a0.x; acc[1]  += pv*a0.y; acc[2]  += pv*a0.z; acc[3]  += pv*a0.w;
        acc[4]  += pv*a1.x; acc[5]  += pv*a1.y; acc[6]  += pv*a1.z; acc[7]  += pv*a1.w;
        acc[8]  += pv*a2.x; acc[9]  += pv*a2.y; acc[10] += pv*a2.z; acc[11] += pv*a2.w;
        acc[12] += pv*a3.x; acc[13] += pv*a3.y; acc[14] += pv*a3.z; acc[15] += pv*a3.w;
      }
      __syncthreads();
    }
  }
  if (outDirect) {
    float wd = 1.0f / (wsum + FEPS);
    float* op = outDirect + ((qi*BS + row)*H + h)*D + c0;
    *(float4*)(op + 0)  = make_float4(acc[0]*wd,  acc[1]*wd,  acc[2]*wd,  acc[3]*wd);
    *(float4*)(op + 4)  = make_float4(acc[4]*wd,  acc[5]*wd,  acc[6]*wd,  acc[7]*wd);
    *(float4*)(op + 8)  = make_float4(acc[8]*wd,  acc[9]*wd,  acc[10]*wd, acc[11]*wd);
    *(float4*)(op + 12) = make_float4(acc[12]*wd, acc[13]*wd, acc[14]*wd, acc[15]*wd);
  } else {
    float* pa = pacc + ((size_t)blockIdx.x*64 + row)*64 + c0;
    *(float4*)(pa + 0)  = make_float4(acc[0],  acc[1],  acc[2],  acc[3]);
    *(float4*)(pa + 4)  = make_float4(acc[4],  acc[5],  acc[6],  acc[7]);
    *(float4*)(pa + 8)  = make_float4(acc[8],  acc[9],  acc[10], acc[11]);
    *(float4*)(pa + 12) = make_float4(acc[12], acc[13], acc[14], acc[15]);
    if (cg == 0) pwsum[(size_t)blockIdx.x*64 + row] = wsum;
  }
}

// ---------------- Kernel R: combine split-K partials + normalize ----------------
__global__ __launch_bounds__(256) void reduce_kernel(const float* __restrict__ pacc,
                                                     const float* __restrict__ pwsum,
                                                     float* __restrict__ out, int ksplit) {
  int bid = blockIdx.x;             // h*NB + qi
  int h = bid >> 5, qi = bid & 31;
  int tid = threadIdx.x;
  int row = tid >> 2, c0 = (tid & 3)*16;
  float acc[16];
#pragma unroll
  for (int j = 0; j < 16; ++j) acc[j] = 0.f;
  float ws = 0.f;
  for (int s = 0; s < ksplit; ++s) {
    const float* pa = pacc + ((size_t)(s*256 + bid)*64 + row)*64 + c0;
    float4 a0 = ((const float4*)pa)[0], a1 = ((const float4*)pa)[1];
    float4 a2 = ((const float4*)pa)[2], a3 = ((const float4*)pa)[3];
    acc[0]  += a0.x; acc[1]  += a0.y; acc[2]  += a0.z; acc[3]  += a0.w;
    acc[4]  += a1.x; acc[5]  += a1.y; acc[6]  += a1.z; acc[7]  += a1.w;
    acc[8]  += a2.x; acc[9]  += a2.y; acc[10] += a2.z; acc[11] += a2.w;
    acc[12] += a3.x; acc[13] += a3.y; acc[14] += a3.z; acc[15] += a3.w;
    ws += pwsum[(size_t)(s*256 + bid)*64 + row];
  }
  float wd = 1.0f / (ws + FEPS);
  float* op = out + ((qi*BS + row)*H + h)*D + c0;
  *(float4*)(op + 0)  = make_float4(acc[0]*wd,  acc[1]*wd,  acc[2]*wd,  acc[3]*wd);
  *(float4*)(op + 4)  = make_float4(acc[4]*wd,  acc[5]*wd,  acc[6]*wd,  acc[7]*wd);
  *(float4*)(op + 8)  = make_float4(acc[8]*wd,  acc[9]*wd,  acc[10]*wd, acc[11]*wd);
  *(float4*)(op + 12) = make_float4(acc[12]*wd, acc[13]*wd, acc[14]*wd, acc[15]*wd);
}

extern "C" void kernel_launch(void* const* d_in, const int* in_sizes, int n_in,
                              void* d_out, int out_size, void* d_ws, size_t ws_size,
                              hipStream_t stream) {
  const float* q = (const float*)d_in[0];
  const float* k = (const float*)d_in[1];
  const float* v = (const float*)d_in[2];
  float* out = (float*)d_out;
  char* ws = (char*)d_ws;
  double* qrep = (double*)(ws + 0);         // 16384 doubles
  double* krep = (double*)(ws + 131072);    // 16384 doubles
  int*    flg  = (int*)   (ws + 262144);    // 256 ints
  float*  ksw  = (float*) (ws + 263168);    // 16384 floats
  float*  kvw  = (float*) (ws + 328704);    // 1048576 floats
  double* bsc  = (double*)(ws + 4523008);   // 8192 doubles
  float*  pws  = (float*) (ws + 4588544);   // KSPLIT*256*64 floats (<= 262144 B)
  float*  pac  = (float*) (ws + 4850688);   // KSPLIT*256*4096 floats

  size_t base = 4850688;
  int ksplit = (ws_size >= base + 4ull*4194304) ? 4
             : (ws_size >= base + 2ull*4194304) ? 2
             : (ws_size >= base + 1ull*4194304) ? 1 : 0;

  prep_kernel<<<512, 256, 0, stream>>>(q, k, v, kvw, ksw, qrep, krep);
  bscore_kernel<<<32, 256, 0, stream>>>(qrep, krep, bsc);
  classify2_kernel<<<1, 256, 0, stream>>>(bsc, flg);
  if (ksplit >= 1) {
    main_kernel<<<ksplit*256, 256, 0, stream>>>(q, k, v, kvw, ksw, flg,
                                                pac, pws, nullptr, NB/ksplit);
    reduce_kernel<<<256, 256, 0, stream>>>(pac, pws, out, ksplit);
  } else {
    main_kernel<<<256, 256, 0, stream>>>(q, k, v, kvw, ksw, flg,
                                         nullptr, nullptr, out, NB);
  }
}

// Round 4
// 120.715 us; speedup vs baseline: 2.9507x; 1.4993x over previous
//
#include <hip/hip_runtime.h>
#include <math.h>

namespace {
constexpr int H  = 8;
constexpr int D  = 64;
constexpr int NB = 32;   // number of 64-blocks along T
constexpr int BS = 64;   // block size
constexpr int QST = 68;  // padded LDS stride (critical path)
}
#define FEPS 1e-6f

typedef unsigned short u16;
typedef unsigned int   u32;
typedef __attribute__((ext_vector_type(8))) short bf16x8;
typedef __attribute__((ext_vector_type(4))) float floatx4;

__device__ __forceinline__ u32 f2bf(float x) {
  union { float f; u32 u; } v; v.f = x;
  return (v.u + 0x7FFFu + ((v.u >> 16) & 1u)) >> 16;
}
__device__ __forceinline__ u32 pk2(float a, float b) { return f2bf(a) | (f2bf(b) << 16); }
#define ELU1(x) ((x) > 0.f ? (x) + 1.f : expf(x))
// XOR swizzle at 8-ushort granularity: row-major [64][64] bf16 tile
#define SWZ(row, kblk) ((row)*64 + (((kblk) ^ ((row)&7))*8))

// ---------------- Kernel P: fused prologue ----------------
// blocks 0..255  : kvT[c][d] = (elu(k)+1)^T v (transposed), k_sum, krep (f64 mean of k)
// blocks 256..511: qrep (f64 block mean of q)
__global__ __launch_bounds__(256) void prep_kernel(const float* __restrict__ q,
                                                   const float* __restrict__ k,
                                                   const float* __restrict__ v,
                                                   float* __restrict__ kvt,
                                                   float* __restrict__ ksum,
                                                   double* __restrict__ qrep,
                                                   double* __restrict__ krep) {
  __shared__ float smem[3*BS*D];          // 48 KB
  int bid = blockIdx.x;
  int tid = threadIdx.x;
  if (bid >= 256) {
    // ---- q block means ----
    double* qred = (double*)smem;
    int r = bid - 256;                    // h*NB + bi
    int h = r >> 5, bi = r & 31;
    int d = tid & 63, quarter = tid >> 6;
    double s = 0.0;
    for (int t = quarter*16; t < quarter*16 + 16; ++t)
      s += (double)q[((bi*BS + t)*H + h)*D + d];
    qred[quarter*64 + d] = s;
    __syncthreads();
    if (tid < 64)
      qrep[r*D + tid] = (qred[tid] + qred[64+tid] + qred[128+tid] + qred[192+tid]) * (1.0/64.0);
    return;
  }
  // ---- kv path ----
  float* kf   = smem;                     // [s][d] elu(k)+1
  float* vv   = smem + BS*D;              // [s][c]
  float* kraw = smem + 2*BS*D;            // [s][d] raw k
  int h = bid >> 5, ki = bid & 31;
  int sr = tid >> 2, cg = tid & 3;
  const float4* kb = (const float4*)(k + ((ki*BS + sr)*H + h)*D);
  const float4* vb = (const float4*)(v + ((ki*BS + sr)*H + h)*D);
#pragma unroll
  for (int m = 0; m < 4; ++m) {
    float4 kk = kb[cg*4 + m];
    float4 vx = vb[cg*4 + m];
    int c = cg*16 + m*4;
    *(float4*)&kraw[sr*D + c] = kk;
    kf[sr*D + c + 0] = ELU1(kk.x);
    kf[sr*D + c + 1] = ELU1(kk.y);
    kf[sr*D + c + 2] = ELU1(kk.z);
    kf[sr*D + c + 3] = ELU1(kk.w);
    *(float4*)&vv[sr*D + c] = vx;
  }
  __syncthreads();
  // thread owns (c = tid&63, d0 = (tid>>6)*16): kvT[c][d0..d0+15] = sum_s kf[s][d]*v[s][c]
  int c = tid & 63, dg = tid >> 6, d0 = dg*16;
  float acc[16];
#pragma unroll
  for (int j = 0; j < 16; ++j) acc[j] = 0.f;
#pragma unroll 4
  for (int s2 = 0; s2 < BS; ++s2) {
    float vval = vv[s2*D + c];
    const float4* kr = (const float4*)&kf[s2*D + d0];
    float4 a0 = kr[0], a1 = kr[1], a2 = kr[2], a3 = kr[3];
    acc[0]  += vval*a0.x; acc[1]  += vval*a0.y; acc[2]  += vval*a0.z; acc[3]  += vval*a0.w;
    acc[4]  += vval*a1.x; acc[5]  += vval*a1.y; acc[6]  += vval*a1.z; acc[7]  += vval*a1.w;
    acc[8]  += vval*a2.x; acc[9]  += vval*a2.y; acc[10] += vval*a2.z; acc[11] += vval*a2.w;
    acc[12] += vval*a3.x; acc[13] += vval*a3.y; acc[14] += vval*a3.z; acc[15] += vval*a3.w;
  }
  float* op = kvt + (size_t)bid*4096 + c*64 + d0;
  *(float4*)(op + 0)  = make_float4(acc[0],  acc[1],  acc[2],  acc[3]);
  *(float4*)(op + 4)  = make_float4(acc[4],  acc[5],  acc[6],  acc[7]);
  *(float4*)(op + 8)  = make_float4(acc[8],  acc[9],  acc[10], acc[11]);
  *(float4*)(op + 12) = make_float4(acc[12], acc[13], acc[14], acc[15]);
  if (dg == 0) {
    float ks = 0.f;
    for (int s2 = 0; s2 < BS; ++s2) ks += kf[s2*D + c];
    ksum[bid*D + c] = ks;
    double m = 0.0;
    for (int s2 = 0; s2 < BS; ++s2) m += (double)kraw[s2*D + c];
    krep[bid*D + c] = m * (1.0/64.0);
  }
}

// ---------------- Kernel B1: bscores (parallel f64 dots) ----------------
__global__ __launch_bounds__(256) void bscore_kernel(const double* __restrict__ qrep,
                                                     const double* __restrict__ krep,
                                                     double* __restrict__ bsc) {
  int tid = threadIdx.x;
  int lr = tid >> 5, ki = tid & 31;
  int r = blockIdx.x * 8 + lr;
  int h = r >> 5;
  const double* qr = qrep + r*D;
  const double* kr = krep + (h*NB + ki)*D;
  double s = 0.0;
#pragma unroll 16
  for (int d = 0; d < D; ++d) s += qr[d]*kr[d];
  bsc[r*NB + ki] = s * 0.125;
}

// ---------------- Kernel B2: classification (single block, streaming, f64) ----------------
__global__ __launch_bounds__(256) void classify2_kernel(const double* __restrict__ bsc,
                                                        int* __restrict__ flags) {
  __shared__ double red[256];
  int tid = threadIdx.x;
  const double* row = bsc + tid*NB;
  double rmax = -1.0e300, rmin = 1.0e300;
#pragma unroll 8
  for (int i = 0; i < NB; ++i) { double b = row[i]; rmax = fmax(rmax, b); rmin = fmin(rmin, b); }
  red[tid] = rmin; __syncthreads();
  for (int s = 128; s > 0; s >>= 1) { if (tid < s) red[tid] = fmin(red[tid], red[tid+s]); __syncthreads(); }
  double gmin = red[0]; __syncthreads();
  double S = 0.0;
#pragma unroll 8
  for (int i = 0; i < NB; ++i) S += exp(row[i] - rmax);
  double invS = 1.0 / S;
  double psum = 0.0;
#pragma unroll 8
  for (int i = 0; i < NB; ++i) psum += exp(row[i] - rmax) * invS;
  double mu = psum * (1.0/32.0);
  double var = 0.0;
#pragma unroll 8
  for (int i = 0; i < NB; ++i) {
    double dv = exp(row[i] - rmax) * invS - mu;
    var += dv*dv;
  }
  var *= (1.0/31.0);
  double rng = rmax - gmin;
  if (rng < 1e-6) rng = 1e-6;
  double imp = var * rng;
  red[tid] = imp; __syncthreads();
  for (int s = 128; s > 0; s >>= 1) { if (tid < s) red[tid] = fmin(red[tid], red[tid+s]); __syncthreads(); }
  double imin = red[0]; __syncthreads();
  red[tid] = imp; __syncthreads();
  for (int s = 128; s > 0; s >>= 1) { if (tid < s) red[tid] = fmax(red[tid], red[tid+s]); __syncthreads(); }
  double imax = red[0];
  double impn = (imp - imin) / (imax - imin + 1e-6);
  flags[tid] = (impn >= 0.5) ? 2 : ((impn <= 0.01) ? 0 : 1);
}

// ---------------- Kernel D: main, split-K over ki; marginal path uses bf16 MFMA ----------------
__global__ __launch_bounds__(256) void main_kernel(
    const float* __restrict__ q, const float* __restrict__ k, const float* __restrict__ v,
    const float* __restrict__ kvt, const float* __restrict__ ksum,
    const int* __restrict__ flags,
    float* __restrict__ pacc, float* __restrict__ pwsum,
    float* __restrict__ outDirect, int kn) {
  __shared__ float smem[8768];            // 35072 B
  int bid = blockIdx.x & 255;
  int chunk = blockIdx.x >> 8;
  int k0 = chunk * kn;
  int h = bid >> 5, qi = bid & 31;
  int tid = threadIdx.x;
  int row = tid >> 2, cg = tid & 3, c0 = cg*16;
  int lane = tid & 63;
  int flag = flags[bid];

  if (flag == 1) {
    // ======== marginal: linear (ELU+1) attention via bf16 MFMA ========
    u16*  qfb  = (u16*)smem;              // [64][64] bf16, XOR-swizzled
    u16*  kvb  = (u16*)(smem + 2048);     // [64][64] bf16, XOR-swizzled
    float* idens = smem + 4096;           // [64][32] 1/den
    float* wsl   = smem + 6144;           // [64] sum of den
    float* kslc  = smem + 6208;           // [kn][64] k_sum

    // stage k_sum chunk
    {
      const float4* kss = (const float4*)(ksum + (size_t)(h*NB + k0)*D);
      for (int i = tid; i < kn*16; i += 256) ((float4*)kslc)[i] = kss[i];
    }
    // load q row, compute qf in f32 regs, store bf16 tile
    float qf[16];
    {
      const float4* qp = (const float4*)(q + ((qi*BS + row)*H + h)*D + c0);
      float4 q0 = qp[0], q1 = qp[1], q2 = qp[2], q3 = qp[3];
      qf[0]=ELU1(q0.x); qf[1]=ELU1(q0.y); qf[2]=ELU1(q0.z); qf[3]=ELU1(q0.w);
      qf[4]=ELU1(q1.x); qf[5]=ELU1(q1.y); qf[6]=ELU1(q1.z); qf[7]=ELU1(q1.w);
      qf[8]=ELU1(q2.x); qf[9]=ELU1(q2.y); qf[10]=ELU1(q2.z); qf[11]=ELU1(q2.w);
      qf[12]=ELU1(q3.x); qf[13]=ELU1(q3.y); qf[14]=ELU1(q3.z); qf[15]=ELU1(q3.w);
      uint4 p0, p1;
      p0.x = pk2(qf[0],qf[1]);  p0.y = pk2(qf[2],qf[3]);
      p0.z = pk2(qf[4],qf[5]);  p0.w = pk2(qf[6],qf[7]);
      p1.x = pk2(qf[8],qf[9]);  p1.y = pk2(qf[10],qf[11]);
      p1.z = pk2(qf[12],qf[13]); p1.w = pk2(qf[14],qf[15]);
      *(uint4*)&qfb[SWZ(row, cg*2)]     = p0;
      *(uint4*)&qfb[SWZ(row, cg*2 + 1)] = p1;
    }
    __syncthreads();
    // den[row][ki] in exact f32: partial over this thread's 16 cols, shfl-reduce over 4 lanes
    {
      float wloc = 0.f;
      for (int ki = 0; ki < kn; ++ki) {
        float pd = 0.f;
#pragma unroll
        for (int j = 0; j < 16; ++j) pd += qf[j] * kslc[ki*64 + c0 + j];
        pd += __shfl_xor(pd, 1, 64);
        pd += __shfl_xor(pd, 2, 64);
        float den = pd + FEPS;
        if (cg == 0) idens[row*32 + ki] = 1.0f / den;
        wloc += den;
      }
      if (cg == 0) wsl[row] = wloc;
    }
    __syncthreads();
    // MFMA fragments: A = qf (fixed per block), B = kv_ki (staged per ki)
    int w = tid >> 6, m = lane & 15, quad = lane >> 4;
    bf16x8 aLo = *(const bf16x8*)&qfb[SWZ(w*16 + m, quad)];
    bf16x8 aHi = *(const bf16x8*)&qfb[SWZ(w*16 + m, 4 + quad)];
    const bf16x8* bLo[4]; const bf16x8* bHi[4];
#pragma unroll
    for (int t = 0; t < 4; ++t) {
      bLo[t] = (const bf16x8*)&kvb[SWZ(t*16 + m, quad)];
      bHi[t] = (const bf16x8*)&kvb[SWZ(t*16 + m, 4 + quad)];
    }
    int rbase = w*16 + quad*4;
    float acc[16];
#pragma unroll
    for (int j = 0; j < 16; ++j) acc[j] = 0.f;

    for (int ki = 0; ki < kn; ++ki) {
      // stage kv_ki tile as bf16 (kvT layout: [c][d], contiguous in d)
      const float4* kvp = (const float4*)(kvt + (size_t)(h*NB + k0 + ki)*4096 + row*64 + c0);
      float4 a0 = kvp[0], a1 = kvp[1], a2 = kvp[2], a3 = kvp[3];
      uint4 p0, p1;
      p0.x = pk2(a0.x,a0.y); p0.y = pk2(a0.z,a0.w);
      p0.z = pk2(a1.x,a1.y); p0.w = pk2(a1.z,a1.w);
      p1.x = pk2(a2.x,a2.y); p1.y = pk2(a2.z,a2.w);
      p1.z = pk2(a3.x,a3.y); p1.w = pk2(a3.z,a3.w);
      *(uint4*)&kvb[SWZ(row, cg*2)]     = p0;
      *(uint4*)&kvb[SWZ(row, cg*2 + 1)] = p1;
      __syncthreads();
      float i0 = idens[(rbase + 0)*32 + ki];
      float i1 = idens[(rbase + 1)*32 + ki];
      float i2 = idens[(rbase + 2)*32 + ki];
      float i3 = idens[(rbase + 3)*32 + ki];
      floatx4 zz = {0.f, 0.f, 0.f, 0.f};
#pragma unroll
      for (int t = 0; t < 4; ++t) {
        floatx4 c4 = __builtin_amdgcn_mfma_f32_16x16x32_bf16(aLo, *bLo[t], zz, 0, 0, 0);
        c4 = __builtin_amdgcn_mfma_f32_16x16x32_bf16(aHi, *bHi[t], c4, 0, 0, 0);
        acc[t*4+0] += c4[0]*i0;
        acc[t*4+1] += c4[1]*i1;
        acc[t*4+2] += c4[2]*i2;
        acc[t*4+3] += c4[3]*i3;
      }
      __syncthreads();
    }
    // epilogue (C layout: row = rbase+r, col = t*16+m)
    if (outDirect) {
#pragma unroll
      for (int r = 0; r < 4; ++r) {
        float wd = 1.0f / (wsl[rbase + r] + FEPS);
        float* op = outDirect + ((qi*BS + rbase + r)*H + h)*D + m;
#pragma unroll
        for (int t = 0; t < 4; ++t) op[t*16] = acc[t*4+r]*wd;
      }
    } else {
#pragma unroll
      for (int r = 0; r < 4; ++r) {
        float* pa = pacc + ((size_t)blockIdx.x*64 + rbase + r)*64 + m;
#pragma unroll
        for (int t = 0; t < 4; ++t) pa[t*16] = acc[t*4+r];
      }
      if (tid < 64) pwsum[(size_t)blockIdx.x*64 + tid] = wsl[tid];
    }
    return;
  }

  // ======== critical / negligible: R3 f32 path ========
  float* bufA = smem;                 // [QST*64]
  float* bufB = smem + 4352;          // [QST*64]
  float acc[16];
#pragma unroll
  for (int j = 0; j < 16; ++j) acc[j] = 0.f;
  float wsum = 0.f;

  if (flag == 2) {
    const float4* qp = (const float4*)(q + ((qi*BS + row)*H + h)*D);
#pragma unroll
    for (int mm = 0; mm < 4; ++mm) {
      float4 qq = qp[cg*4 + mm];
      int c = c0 + mm*4;
      bufA[row*QST + c + 0] = qq.x*0.125f;
      bufA[row*QST + c + 1] = qq.y*0.125f;
      bufA[row*QST + c + 2] = qq.z*0.125f;
      bufA[row*QST + c + 3] = qq.w*0.125f;
    }
    __syncthreads();
    for (int ki = k0; ki < k0 + kn; ++ki) {
      const float4* kp = (const float4*)(k + ((ki*BS + row)*H + h)*D);
#pragma unroll
      for (int mm = 0; mm < 4; ++mm)
        *(float4*)&bufB[row*QST + c0 + mm*4] = kp[cg*4 + mm];
      __syncthreads();
      float sc[16];
#pragma unroll
      for (int j = 0; j < 16; ++j) sc[j] = 0.f;
      for (int d = 0; d < D; ++d) {
        float a = bufA[row*QST + d];
#pragma unroll
        for (int j = 0; j < 16; ++j)
          sc[j] += a * bufB[(c0 + j)*QST + d];
      }
      float mx = sc[0];
#pragma unroll
      for (int j = 1; j < 16; ++j) mx = fmaxf(mx, sc[j]);
      mx = fmaxf(mx, __shfl_xor(mx, 1, 64));
      mx = fmaxf(mx, __shfl_xor(mx, 2, 64));
      float es = 0.f;
      float p[16];
#pragma unroll
      for (int j = 0; j < 16; ++j) { p[j] = expf(sc[j] - mx); es += p[j]; }
      es += __shfl_xor(es, 1, 64);
      es += __shfl_xor(es, 2, 64);
      float inv = 1.0f / es;
#pragma unroll
      for (int j = 0; j < 16; ++j) p[j] *= inv;
      wsum += es * inv;
      __syncthreads();
      const float4* vp = (const float4*)(v + ((ki*BS + row)*H + h)*D);
#pragma unroll
      for (int mm = 0; mm < 4; ++mm)
        *(float4*)&bufB[row*QST + c0 + mm*4] = vp[cg*4 + mm];
      __syncthreads();
      for (int s2 = 0; s2 < BS; ++s2) {
        int g = s2 >> 4, jj = s2 & 15;
        float pv = __shfl(p[jj], (lane & ~3) | g, 64);
        const float4* vr = (const float4*)&bufB[s2*QST + c0];
        float4 a0 = vr[0], a1 = vr[1], a2 = vr[2], a3 = vr[3];
        acc[0]  += pv*a0.x; acc[1]  += pv*a0.y; acc[2]  += pv*a0.z; acc[3]  += pv*a0.w;
        acc[4]  += pv*a1.x; acc[5]  += pv*a1.y; acc[6]  += pv*a1.z; acc[7]  += pv*a1.w;
        acc[8]  += pv*a2.x; acc[9]  += pv*a2.y; acc[10] += pv*a2.z; acc[11] += pv*a2.w;
        acc[12] += pv*a3.x; acc[13] += pv*a3.y; acc[14] += pv*a3.z; acc[15] += pv*a3.w;
      }
      __syncthreads();
    }
  }
  if (outDirect) {
    float wd = 1.0f / (wsum + FEPS);
    float* op = outDirect + ((qi*BS + row)*H + h)*D + c0;
    *(float4*)(op + 0)  = make_float4(acc[0]*wd,  acc[1]*wd,  acc[2]*wd,  acc[3]*wd);
    *(float4*)(op + 4)  = make_float4(acc[4]*wd,  acc[5]*wd,  acc[6]*wd,  acc[7]*wd);
    *(float4*)(op + 8)  = make_float4(acc[8]*wd,  acc[9]*wd,  acc[10]*wd, acc[11]*wd);
    *(float4*)(op + 12) = make_float4(acc[12]*wd, acc[13]*wd, acc[14]*wd, acc[15]*wd);
  } else {
    float* pa = pacc + ((size_t)blockIdx.x*64 + row)*64 + c0;
    *(float4*)(pa + 0)  = make_float4(acc[0],  acc[1],  acc[2],  acc[3]);
    *(float4*)(pa + 4)  = make_float4(acc[4],  acc[5],  acc[6],  acc[7]);
    *(float4*)(pa + 8)  = make_float4(acc[8],  acc[9],  acc[10], acc[11]);
    *(float4*)(pa + 12) = make_float4(acc[12], acc[13], acc[14], acc[15]);
    if (cg == 0) pwsum[(size_t)blockIdx.x*64 + row] = wsum;
  }
}

// ---------------- Kernel R: combine split-K partials + normalize ----------------
__global__ __launch_bounds__(256) void reduce_kernel(const float* __restrict__ pacc,
                                                     const float* __restrict__ pwsum,
                                                     float* __restrict__ out, int ksplit) {
  int bid = blockIdx.x;
  int h = bid >> 5, qi = bid & 31;
  int tid = threadIdx.x;
  int row = tid >> 2, c0 = (tid & 3)*16;
  float acc[16];
#pragma unroll
  for (int j = 0; j < 16; ++j) acc[j] = 0.f;
  float ws = 0.f;
  for (int s = 0; s < ksplit; ++s) {
    const float* pa = pacc + ((size_t)(s*256 + bid)*64 + row)*64 + c0;
    float4 a0 = ((const float4*)pa)[0], a1 = ((const float4*)pa)[1];
    float4 a2 = ((const float4*)pa)[2], a3 = ((const float4*)pa)[3];
    acc[0]  += a0.x; acc[1]  += a0.y; acc[2]  += a0.z; acc[3]  += a0.w;
    acc[4]  += a1.x; acc[5]  += a1.y; acc[6]  += a1.z; acc[7]  += a1.w;
    acc[8]  += a2.x; acc[9]  += a2.y; acc[10] += a2.z; acc[11] += a2.w;
    acc[12] += a3.x; acc[13] += a3.y; acc[14] += a3.z; acc[15] += a3.w;
    ws += pwsum[(size_t)(s*256 + bid)*64 + row];
  }
  float wd = 1.0f / (ws + FEPS);
  float* op = out + ((qi*BS + row)*H + h)*D + c0;
  *(float4*)(op + 0)  = make_float4(acc[0]*wd,  acc[1]*wd,  acc[2]*wd,  acc[3]*wd);
  *(float4*)(op + 4)  = make_float4(acc[4]*wd,  acc[5]*wd,  acc[6]*wd,  acc[7]*wd);
  *(float4*)(op + 8)  = make_float4(acc[8]*wd,  acc[9]*wd,  acc[10]*wd, acc[11]*wd);
  *(float4*)(op + 12) = make_float4(acc[12]*wd, acc[13]*wd, acc[14]*wd, acc[15]*wd);
}

extern "C" void kernel_launch(void* const* d_in, const int* in_sizes, int n_in,
                              void* d_out, int out_size, void* d_ws, size_t ws_size,
                              hipStream_t stream) {
  const float* q = (const float*)d_in[0];
  const float* k = (const float*)d_in[1];
  const float* v = (const float*)d_in[2];
  float* out = (float*)d_out;
  char* ws = (char*)d_ws;
  double* qrep = (double*)(ws + 0);         // 16384 doubles
  double* krep = (double*)(ws + 131072);    // 16384 doubles
  int*    flg  = (int*)   (ws + 262144);    // 256 ints
  float*  ksw  = (float*) (ws + 263168);    // 16384 floats
  float*  kvw  = (float*) (ws + 328704);    // 1048576 floats (transposed [bid][c][d])
  double* bsc  = (double*)(ws + 4523008);   // 8192 doubles
  float*  pws  = (float*) (ws + 4588544);   // KSPLIT*256*64 floats
  float*  pac  = (float*) (ws + 4850688);   // KSPLIT*256*4096 floats

  size_t base = 4850688;
  int ksplit = (ws_size >= base + 4ull*4194304) ? 4
             : (ws_size >= base + 2ull*4194304) ? 2
             : (ws_size >= base + 1ull*4194304) ? 1 : 0;

  prep_kernel<<<512, 256, 0, stream>>>(q, k, v, kvw, ksw, qrep, krep);
  bscore_kernel<<<32, 256, 0, stream>>>(qrep, krep, bsc);
  classify2_kernel<<<1, 256, 0, stream>>>(bsc, flg);
  if (ksplit >= 1) {
    main_kernel<<<ksplit*256, 256, 0, stream>>>(q, k, v, kvw, ksw, flg,
                                                pac, pws, nullptr, NB/ksplit);
    reduce_kernel<<<256, 256, 0, stream>>>(pac, pws, out, ksplit);
  } else {
    main_kernel<<<256, 256, 0, stream>>>(q, k, v, kvw, ksw, flg,
                                         nullptr, nullptr, out, NB);
  }
}

// Round 5
// 109.720 us; speedup vs baseline: 3.2464x; 1.1002x over previous
//
#include <hip/hip_runtime.h>
#include <math.h>

namespace {
constexpr int H  = 8;
constexpr int D  = 64;
constexpr int NB = 32;   // number of 64-blocks along T
constexpr int BS = 64;   // block size
constexpr int QST = 68;  // padded LDS stride (critical path)
}
#define FEPS 1e-6f

typedef unsigned short u16;
typedef unsigned int   u32;
typedef __attribute__((ext_vector_type(8))) short bf16x8;
typedef __attribute__((ext_vector_type(4))) float floatx4;

__device__ __forceinline__ u32 f2bf(float x) {
  union { float f; u32 u; } v; v.f = x;
  return (v.u + 0x7FFFu + ((v.u >> 16) & 1u)) >> 16;
}
__device__ __forceinline__ u32 pk2(float a, float b) { return f2bf(a) | (f2bf(b) << 16); }
#define ELU1(x) ((x) > 0.f ? (x) + 1.f : expf(x))
// XOR swizzle at 8-ushort granularity: row-major [64][64] bf16 tile
#define SWZ(row, kblk) ((row)*64 + (((kblk) ^ ((row)&7))*8))

// ---------------- Kernel P: fused prologue ----------------
// blocks 0..255  : kvT[c][d] = (elu(k)+1)^T v (transposed), k_sum, krep (f64 mean of k)
// blocks 256..511: qrep (f64 block mean of q)
__global__ __launch_bounds__(256) void prep_kernel(const float* __restrict__ q,
                                                   const float* __restrict__ k,
                                                   const float* __restrict__ v,
                                                   float* __restrict__ kvt,
                                                   float* __restrict__ ksum,
                                                   double* __restrict__ qrep,
                                                   double* __restrict__ krep) {
  __shared__ float smem[3*BS*D];          // 48 KB
  int bid = blockIdx.x;
  int tid = threadIdx.x;
  if (bid >= 256) {
    // ---- q block means ----
    double* qred = (double*)smem;
    int r = bid - 256;                    // h*NB + bi
    int h = r >> 5, bi = r & 31;
    int d = tid & 63, quarter = tid >> 6;
    double s = 0.0;
    for (int t = quarter*16; t < quarter*16 + 16; ++t)
      s += (double)q[((bi*BS + t)*H + h)*D + d];
    qred[quarter*64 + d] = s;
    __syncthreads();
    if (tid < 64)
      qrep[r*D + tid] = (qred[tid] + qred[64+tid] + qred[128+tid] + qred[192+tid]) * (1.0/64.0);
    return;
  }
  // ---- kv path ----
  float* kf   = smem;                     // [s][d] elu(k)+1
  float* vv   = smem + BS*D;              // [s][c]
  float* kraw = smem + 2*BS*D;            // [s][d] raw k
  int h = bid >> 5, ki = bid & 31;
  int sr = tid >> 2, cg = tid & 3;
  const float4* kb = (const float4*)(k + ((ki*BS + sr)*H + h)*D);
  const float4* vb = (const float4*)(v + ((ki*BS + sr)*H + h)*D);
#pragma unroll
  for (int m = 0; m < 4; ++m) {
    float4 kk = kb[cg*4 + m];
    float4 vx = vb[cg*4 + m];
    int c = cg*16 + m*4;
    *(float4*)&kraw[sr*D + c] = kk;
    kf[sr*D + c + 0] = ELU1(kk.x);
    kf[sr*D + c + 1] = ELU1(kk.y);
    kf[sr*D + c + 2] = ELU1(kk.z);
    kf[sr*D + c + 3] = ELU1(kk.w);
    *(float4*)&vv[sr*D + c] = vx;
  }
  __syncthreads();
  // thread owns (c = tid&63, d0 = (tid>>6)*16): kvT[c][d0..d0+15] = sum_s kf[s][d]*v[s][c]
  int c = tid & 63, dg = tid >> 6, d0 = dg*16;
  float acc[16];
#pragma unroll
  for (int j = 0; j < 16; ++j) acc[j] = 0.f;
#pragma unroll 4
  for (int s2 = 0; s2 < BS; ++s2) {
    float vval = vv[s2*D + c];
    const float4* kr = (const float4*)&kf[s2*D + d0];
    float4 a0 = kr[0], a1 = kr[1], a2 = kr[2], a3 = kr[3];
    acc[0]  += vval*a0.x; acc[1]  += vval*a0.y; acc[2]  += vval*a0.z; acc[3]  += vval*a0.w;
    acc[4]  += vval*a1.x; acc[5]  += vval*a1.y; acc[6]  += vval*a1.z; acc[7]  += vval*a1.w;
    acc[8]  += vval*a2.x; acc[9]  += vval*a2.y; acc[10] += vval*a2.z; acc[11] += vval*a2.w;
    acc[12] += vval*a3.x; acc[13] += vval*a3.y; acc[14] += vval*a3.z; acc[15] += vval*a3.w;
  }
  float* op = kvt + (size_t)bid*4096 + c*64 + d0;
  *(float4*)(op + 0)  = make_float4(acc[0],  acc[1],  acc[2],  acc[3]);
  *(float4*)(op + 4)  = make_float4(acc[4],  acc[5],  acc[6],  acc[7]);
  *(float4*)(op + 8)  = make_float4(acc[8],  acc[9],  acc[10], acc[11]);
  *(float4*)(op + 12) = make_float4(acc[12], acc[13], acc[14], acc[15]);
  if (dg == 0) {
    float ks = 0.f;
    for (int s2 = 0; s2 < BS; ++s2) ks += kf[s2*D + c];
    ksum[bid*D + c] = ks;
    double m = 0.0;
    for (int s2 = 0; s2 < BS; ++s2) m += (double)kraw[s2*D + c];
    krep[bid*D + c] = m * (1.0/64.0);
  }
}

// ---------------- Kernel B1: bscores (parallel f64 dots) ----------------
__global__ __launch_bounds__(256) void bscore_kernel(const double* __restrict__ qrep,
                                                     const double* __restrict__ krep,
                                                     double* __restrict__ bsc) {
  int tid = threadIdx.x;
  int lr = tid >> 5, ki = tid & 31;
  int r = blockIdx.x * 8 + lr;
  int h = r >> 5;
  const double* qr = qrep + r*D;
  const double* kr = krep + (h*NB + ki)*D;
  double s = 0.0;
#pragma unroll 16
  for (int d = 0; d < D; ++d) s += qr[d]*kr[d];
  bsc[r*NB + ki] = s * 0.125;
}

// ---------------- Kernel B2: classification (single block, single exp pass, f64) ----------------
__global__ __launch_bounds__(256) void classify3_kernel(const double* __restrict__ bsc,
                                                        int* __restrict__ flags) {
  __shared__ double red[256];
  int tid = threadIdx.x;
  const double* row = bsc + tid*NB;
  double rmax = -1.0e300, rmin = 1.0e300;
#pragma unroll 8
  for (int i = 0; i < NB; ++i) { double b = row[i]; rmax = fmax(rmax, b); rmin = fmin(rmin, b); }
  red[tid] = rmin; __syncthreads();
  for (int s = 128; s > 0; s >>= 1) { if (tid < s) red[tid] = fmin(red[tid], red[tid+s]); __syncthreads(); }
  double gmin = red[0]; __syncthreads();
  // single exp pass: S = sum e, S2 = sum e^2  (var computed algebraically in f64;
  // cancellation leaves ~1e-8 rel err, far below the f32 reference's own noise)
  double S = 0.0, S2 = 0.0;
#pragma unroll 8
  for (int i = 0; i < NB; ++i) { double e = exp(row[i] - rmax); S += e; S2 += e*e; }
  double invS = 1.0 / S;
  double sp = S * invS;                  // ~1.0
  double mu = sp * (1.0/32.0);
  double var = (S2*invS*invS - 2.0*mu*sp + 32.0*mu*mu) * (1.0/31.0);
  double rng = rmax - gmin;
  if (rng < 1e-6) rng = 1e-6;
  double imp = var * rng;
  red[tid] = imp; __syncthreads();
  for (int s = 128; s > 0; s >>= 1) { if (tid < s) red[tid] = fmin(red[tid], red[tid+s]); __syncthreads(); }
  double imin = red[0]; __syncthreads();
  red[tid] = imp; __syncthreads();
  for (int s = 128; s > 0; s >>= 1) { if (tid < s) red[tid] = fmax(red[tid], red[tid+s]); __syncthreads(); }
  double imax = red[0];
  double impn = (imp - imin) / (imax - imin + 1e-6);
  flags[tid] = (impn >= 0.5) ? 2 : ((impn <= 0.01) ? 0 : 1);
}

// ---------------- Kernel D: main, one block per (h,qblock), direct output ----------------
__global__ __launch_bounds__(256) void main_kernel(
    const float* __restrict__ q, const float* __restrict__ k, const float* __restrict__ v,
    const float* __restrict__ kvt, const float* __restrict__ ksum,
    const int* __restrict__ flags, float* __restrict__ out) {
  __shared__ float smem[10304];           // 41216 B
  int bid = blockIdx.x;                   // h*NB + qi
  int h = bid >> 5, qi = bid & 31;
  int tid = threadIdx.x;
  int row = tid >> 2, cg = tid & 3, c0 = cg*16;
  int lane = tid & 63;
  int flag = flags[bid];

  if (flag == 1) {
    // ======== marginal: linear (ELU+1) attention via bf16 MFMA, double-buffered ========
    u16*  qfb  = (u16*)smem;              // [64][64] bf16, swizzled          (8 KB)
    u16*  kvb  = (u16*)(smem + 2048);     // 2 x [64][64] bf16, swizzled      (16 KB)
    float* idens = smem + 6144;           // [64][32] 1/den                   (8 KB)
    float* wsl   = smem + 8192;           // [64] sum of den
    float* kslc  = smem + 8256;           // [32][64] k_sum                   (8 KB)

    // stage k_sum for all 32 ki
    {
      const float4* kss = (const float4*)(ksum + (size_t)(h*NB)*D);
      for (int i = tid; i < NB*16; i += 256) ((float4*)kslc)[i] = kss[i];
    }
    // load q row, qf in f32 regs, store bf16 A tile
    float qf[16];
    {
      const float4* qp = (const float4*)(q + ((qi*BS + row)*H + h)*D + c0);
      float4 q0 = qp[0], q1 = qp[1], q2 = qp[2], q3 = qp[3];
      qf[0]=ELU1(q0.x); qf[1]=ELU1(q0.y); qf[2]=ELU1(q0.z); qf[3]=ELU1(q0.w);
      qf[4]=ELU1(q1.x); qf[5]=ELU1(q1.y); qf[6]=ELU1(q1.z); qf[7]=ELU1(q1.w);
      qf[8]=ELU1(q2.x); qf[9]=ELU1(q2.y); qf[10]=ELU1(q2.z); qf[11]=ELU1(q2.w);
      qf[12]=ELU1(q3.x); qf[13]=ELU1(q3.y); qf[14]=ELU1(q3.z); qf[15]=ELU1(q3.w);
      uint4 p0, p1;
      p0.x = pk2(qf[0],qf[1]);  p0.y = pk2(qf[2],qf[3]);
      p0.z = pk2(qf[4],qf[5]);  p0.w = pk2(qf[6],qf[7]);
      p1.x = pk2(qf[8],qf[9]);  p1.y = pk2(qf[10],qf[11]);
      p1.z = pk2(qf[12],qf[13]); p1.w = pk2(qf[14],qf[15]);
      *(uint4*)&qfb[SWZ(row, cg*2)]     = p0;
      *(uint4*)&qfb[SWZ(row, cg*2 + 1)] = p1;
    }
    // prefetch kv tile 0
    const float* kvbase = kvt + (size_t)(h*NB)*4096 + row*64 + c0;
    float4 t0, t1, t2, t3;
    {
      const float4* kvp = (const float4*)kvbase;
      t0 = kvp[0]; t1 = kvp[1]; t2 = kvp[2]; t3 = kvp[3];
    }
    __syncthreads();
    // den[row][ki] exact f32: partial over 16 cols + shfl reduce over 4 lanes
    {
      float wloc = 0.f;
      for (int ki = 0; ki < NB; ++ki) {
        float pd = 0.f;
#pragma unroll
        for (int j = 0; j < 16; ++j) pd += qf[j] * kslc[ki*64 + c0 + j];
        pd += __shfl_xor(pd, 1, 64);
        pd += __shfl_xor(pd, 2, 64);
        float den = pd + FEPS;
        if (cg == 0) idens[row*32 + ki] = 1.0f / den;
        wloc += den;
      }
      if (cg == 0) wsl[row] = wloc;
    }
    // store tile 0 to buffer 0
    {
      uint4 p0, p1;
      p0.x = pk2(t0.x,t0.y); p0.y = pk2(t0.z,t0.w);
      p0.z = pk2(t1.x,t1.y); p0.w = pk2(t1.z,t1.w);
      p1.x = pk2(t2.x,t2.y); p1.y = pk2(t2.z,t2.w);
      p1.z = pk2(t3.x,t3.y); p1.w = pk2(t3.z,t3.w);
      *(uint4*)&kvb[SWZ(row, cg*2)]     = p0;
      *(uint4*)&kvb[SWZ(row, cg*2 + 1)] = p1;
    }
    // A fragments
    int w = tid >> 6, m = lane & 15, quad = lane >> 4;
    bf16x8 aLo = *(const bf16x8*)&qfb[SWZ(w*16 + m, quad)];
    bf16x8 aHi = *(const bf16x8*)&qfb[SWZ(w*16 + m, 4 + quad)];
    int rbase = w*16 + quad*4;
    float acc[16];
#pragma unroll
    for (int j = 0; j < 16; ++j) acc[j] = 0.f;

    for (int ki = 0; ki < NB; ++ki) {
      // prefetch tile ki+1 to regs
      if (ki + 1 < NB) {
        const float4* kvp = (const float4*)(kvbase + (size_t)(ki+1)*4096);
        t0 = kvp[0]; t1 = kvp[1]; t2 = kvp[2]; t3 = kvp[3];
      }
      __syncthreads();                    // tile ki visible; reads of ki-1 done
      const u16* kb = kvb + (ki & 1)*4096;
      float i0 = idens[(rbase + 0)*32 + ki];
      float i1 = idens[(rbase + 1)*32 + ki];
      float i2 = idens[(rbase + 2)*32 + ki];
      float i3 = idens[(rbase + 3)*32 + ki];
      floatx4 zz = {0.f, 0.f, 0.f, 0.f};
#pragma unroll
      for (int t = 0; t < 4; ++t) {
        bf16x8 bLo = *(const bf16x8*)&kb[SWZ(t*16 + m, quad)];
        bf16x8 bHi = *(const bf16x8*)&kb[SWZ(t*16 + m, 4 + quad)];
        floatx4 c4 = __builtin_amdgcn_mfma_f32_16x16x32_bf16(aLo, bLo, zz, 0, 0, 0);
        c4 = __builtin_amdgcn_mfma_f32_16x16x32_bf16(aHi, bHi, c4, 0, 0, 0);
        acc[t*4+0] += c4[0]*i0;
        acc[t*4+1] += c4[1]*i1;
        acc[t*4+2] += c4[2]*i2;
        acc[t*4+3] += c4[3]*i3;
      }
      // pack + store tile ki+1 into the other buffer
      if (ki + 1 < NB) {
        u16* kw = kvb + ((ki+1) & 1)*4096;
        uint4 p0, p1;
        p0.x = pk2(t0.x,t0.y); p0.y = pk2(t0.z,t0.w);
        p0.z = pk2(t1.x,t1.y); p0.w = pk2(t1.z,t1.w);
        p1.x = pk2(t2.x,t2.y); p1.y = pk2(t2.z,t2.w);
        p1.z = pk2(t3.x,t3.y); p1.w = pk2(t3.z,t3.w);
        *(uint4*)&kw[SWZ(row, cg*2)]     = p0;
        *(uint4*)&kw[SWZ(row, cg*2 + 1)] = p1;
      }
    }
    // epilogue (C layout: row = rbase+r, col = t*16+m)
#pragma unroll
    for (int r = 0; r < 4; ++r) {
      float wd = 1.0f / (wsl[rbase + r] + FEPS);
      float* op = out + ((qi*BS + rbase + r)*H + h)*D + m;
#pragma unroll
      for (int t = 0; t < 4; ++t) op[t*16] = acc[t*4+r]*wd;
    }
    return;
  }

  // ======== critical / negligible: f32 path ========
  float* bufA = smem;                 // [QST*64]
  float* bufB = smem + 4352;          // [QST*64]
  float acc[16];
#pragma unroll
  for (int j = 0; j < 16; ++j) acc[j] = 0.f;
  float wsum = 0.f;

  if (flag == 2) {
    const float4* qp = (const float4*)(q + ((qi*BS + row)*H + h)*D);
#pragma unroll
    for (int mm = 0; mm < 4; ++mm) {
      float4 qq = qp[cg*4 + mm];
      int c = c0 + mm*4;
      bufA[row*QST + c + 0] = qq.x*0.125f;
      bufA[row*QST + c + 1] = qq.y*0.125f;
      bufA[row*QST + c + 2] = qq.z*0.125f;
      bufA[row*QST + c + 3] = qq.w*0.125f;
    }
    __syncthreads();
    for (int ki = 0; ki < NB; ++ki) {
      const float4* kp = (const float4*)(k + ((ki*BS + row)*H + h)*D);
#pragma unroll
      for (int mm = 0; mm < 4; ++mm)
        *(float4*)&bufB[row*QST + c0 + mm*4] = kp[cg*4 + mm];
      __syncthreads();
      float sc[16];
#pragma unroll
      for (int j = 0; j < 16; ++j) sc[j] = 0.f;
      for (int d = 0; d < D; ++d) {
        float a = bufA[row*QST + d];
#pragma unroll
        for (int j = 0; j < 16; ++j)
          sc[j] += a * bufB[(c0 + j)*QST + d];
      }
      float mx = sc[0];
#pragma unroll
      for (int j = 1; j < 16; ++j) mx = fmaxf(mx, sc[j]);
      mx = fmaxf(mx, __shfl_xor(mx, 1, 64));
      mx = fmaxf(mx, __shfl_xor(mx, 2, 64));
      float es = 0.f;
      float p[16];
#pragma unroll
      for (int j = 0; j < 16; ++j) { p[j] = expf(sc[j] - mx); es += p[j]; }
      es += __shfl_xor(es, 1, 64);
      es += __shfl_xor(es, 2, 64);
      float inv = 1.0f / es;
#pragma unroll
      for (int j = 0; j < 16; ++j) p[j] *= inv;
      wsum += es * inv;
      __syncthreads();
      const float4* vp = (const float4*)(v + ((ki*BS + row)*H + h)*D);
#pragma unroll
      for (int mm = 0; mm < 4; ++mm)
        *(float4*)&bufB[row*QST + c0 + mm*4] = vp[cg*4 + mm];
      __syncthreads();
      for (int s2 = 0; s2 < BS; ++s2) {
        int g = s2 >> 4, jj = s2 & 15;
        float pv = __shfl(p[jj], (lane & ~3) | g, 64);
        const float4* vr = (const float4*)&bufB[s2*QST + c0];
        float4 a0 = vr[0], a1 = vr[1], a2 = vr[2], a3 = vr[3];
        acc[0]  += pv*a0.x; acc[1]  += pv*a0.y; acc[2]  += pv*a0.z; acc[3]  += pv*a0.w;
        acc[4]  += pv*a1.x; acc[5]  += pv*a1.y; acc[6]  += pv*a1.z; acc[7]  += pv*a1.w;
        acc[8]  += pv*a2.x; acc[9]  += pv*a2.y; acc[10] += pv*a2.z; acc[11] += pv*a2.w;
        acc[12] += pv*a3.x; acc[13] += pv*a3.y; acc[14] += pv*a3.z; acc[15] += pv*a3.w;
      }
      __syncthreads();
    }
  }
  float wd = 1.0f / (wsum + FEPS);
  float* op = out + ((qi*BS + row)*H + h)*D + c0;
  *(float4*)(op + 0)  = make_float4(acc[0]*wd,  acc[1]*wd,  acc[2]*wd,  acc[3]*wd);
  *(float4*)(op + 4)  = make_float4(acc[4]*wd,  acc[5]*wd,  acc[6]*wd,  acc[7]*wd);
  *(float4*)(op + 8)  = make_float4(acc[8]*wd,  acc[9]*wd,  acc[10]*wd, acc[11]*wd);
  *(float4*)(op + 12) = make_float4(acc[12]*wd, acc[13]*wd, acc[14]*wd, acc[15]*wd);
}

extern "C" void kernel_launch(void* const* d_in, const int* in_sizes, int n_in,
                              void* d_out, int out_size, void* d_ws, size_t ws_size,
                              hipStream_t stream) {
  const float* q = (const float*)d_in[0];
  const float* k = (const float*)d_in[1];
  const float* v = (const float*)d_in[2];
  float* out = (float*)d_out;
  char* ws = (char*)d_ws;
  double* qrep = (double*)(ws + 0);         // 16384 doubles
  double* krep = (double*)(ws + 131072);    // 16384 doubles
  int*    flg  = (int*)   (ws + 262144);    // 256 ints
  float*  ksw  = (float*) (ws + 263168);    // 16384 floats
  float*  kvw  = (float*) (ws + 328704);    // 1048576 floats (transposed [bid][c][d])
  double* bsc  = (double*)(ws + 4523008);   // 8192 doubles

  prep_kernel<<<512, 256, 0, stream>>>(q, k, v, kvw, ksw, qrep, krep);
  bscore_kernel<<<32, 256, 0, stream>>>(qrep, krep, bsc);
  classify3_kernel<<<1, 256, 0, stream>>>(bsc, flg);
  main_kernel<<<256, 256, 0, stream>>>(q, k, v, kvw, ksw, flg, out);
}